// Round 1
// baseline (3586.768 us; speedup 1.0000x reference)
//
#include <hip/hip_runtime.h>
#include <cstdint>
#include <cstddef>

// Sizes (fixed by problem, but N/E/G derived at launch)
static constexpr int HD = 200;   // hidden
static constexpr int NH = 8;     // heads
static constexpr int CD = 25;    // per-head dim
static constexpr int NL = 4;     // layers

// ---------------- CSR build ----------------
__global__ __launch_bounds__(256) void k_hist(const int* __restrict__ dst, int* __restrict__ cnt, int E) {
  int e = blockIdx.x * 256 + threadIdx.x;
  if (e < E) atomicAdd(&cnt[dst[e]], 1);
}

__global__ __launch_bounds__(256) void k_scan1(const int* __restrict__ cnt, int* __restrict__ off,
                                               int* __restrict__ partial, int N) {
  __shared__ int sm[256];
  int t = threadIdx.x, i = blockIdx.x * 256 + t;
  int v = (i < N) ? cnt[i] : 0;
  sm[t] = v; __syncthreads();
  for (int o = 1; o < 256; o <<= 1) {
    int add = (t >= o) ? sm[t - o] : 0;
    __syncthreads();
    sm[t] += add;
    __syncthreads();
  }
  if (i < N) off[i] = sm[t] - v;            // exclusive
  if (t == 255) partial[blockIdx.x] = sm[255];
}

__global__ __launch_bounds__(512) void k_scan2(int* __restrict__ partial, int nb, int* __restrict__ off, int N) {
  __shared__ int sm[512];
  int t = threadIdx.x;
  int v = (t < nb) ? partial[t] : 0;
  sm[t] = v; __syncthreads();
  for (int o = 1; o < 512; o <<= 1) {
    int add = (t >= o) ? sm[t - o] : 0;
    __syncthreads();
    sm[t] += add;
    __syncthreads();
  }
  if (t < nb) partial[t] = sm[t] - v;       // exclusive block offsets
  if (t == 511) off[N] = sm[511];           // total == E
}

__global__ __launch_bounds__(256) void k_scan3(int* __restrict__ off, const int* __restrict__ partial, int N) {
  int i = blockIdx.x * 256 + threadIdx.x;
  if (i < N) off[i] += partial[i >> 8];
}

__global__ __launch_bounds__(256) void k_scatter(const int* __restrict__ dst, const int* __restrict__ off,
                                                 int* __restrict__ cur, int* __restrict__ eid, int E) {
  int e = blockIdx.x * 256 + threadIdx.x;
  if (e < E) {
    int d = dst[e];
    int p = atomicAdd(&cur[d], 1);
    eid[off[d] + p] = e;
  }
}

// sort each node's edge list ascending -> deterministic float accumulation order everywhere downstream
__global__ __launch_bounds__(256) void k_sort(const int* __restrict__ off, int* __restrict__ eid, int N) {
  int n = blockIdx.x * 256 + threadIdx.x;
  if (n >= N) return;
  int o0 = off[n], o1 = off[n + 1];
  for (int i = o0 + 1; i < o1; ++i) {
    int v = eid[i]; int j = i - 1;
    while (j >= o0 && eid[j] > v) { eid[j + 1] = eid[j]; --j; }
    eid[j + 1] = v;
  }
}

// ---------------- edge-attention precompute (algebraic reductions) ----------------
__global__ __launch_bounds__(128) void k_meanea(const float* __restrict__ ea, const int* __restrict__ off,
                                                const int* __restrict__ eid, float* __restrict__ mea, int N) {
  int n = blockIdx.x * 128 + threadIdx.x;
  if (n >= N) return;
  int o0 = off[n], o1 = off[n + 1];
  float s0 = 0, s1 = 0, s2 = 0, s3 = 0, s4 = 0, s5 = 0;
  for (int p = o0; p < o1; ++p) {
    const float* r = ea + (size_t)eid[p] * 6;
    s0 += r[0]; s1 += r[1]; s2 += r[2]; s3 += r[3]; s4 += r[4]; s5 += r[5];
  }
  float inv = (o1 > o0) ? 1.f / (float)(o1 - o0) : 0.f;
  float* m = mea + (size_t)n * 6;
  m[0] = s0 * inv; m[1] = s1 * inv; m[2] = s2 * inv; m[3] = s3 * inv; m[4] = s4 * inv; m[5] = s5 * inv;
}

// w_e[l][k][h] = sum_c lin_edge_w[l][k][h*25+c] * att_edge[l][h][c]
__global__ __launch_bounds__(256) void k_we(const float* __restrict__ lew, const float* __restrict__ ae,
                                            float* __restrict__ we) {
  int tid = blockIdx.x * 256 + threadIdx.x;
  if (tid >= NL * HD * 8) return;
  int l = tid / (HD * 8); int r = tid % (HD * 8); int k = r >> 3; int hh = r & 7;
  const float* W = lew + (size_t)l * HD * HD + (size_t)k * HD + hh * CD;
  const float* a = ae + l * NH * CD + hh * CD;
  float s = 0.f;
#pragma unroll
  for (int c = 0; c < CD; ++c) s += W[c] * a[c];
  we[tid] = s;   // layout l*1600 + k*8 + hh
}

// M[l][f][h] = sum_k edge_emb_w[f][k] * w_e[l][k][h];  cvec[l][h] = sum_k edge_emb_b[k]*w_e[l][k][h]
__global__ __launch_bounds__(256) void k_M(const float* __restrict__ ew, const float* __restrict__ eb,
                                           const float* __restrict__ we, float* __restrict__ Mm,
                                           float* __restrict__ cv) {
  int tid = threadIdx.x;
  if (tid < NL * 6 * 8) {
    int l = tid / 48, r = tid % 48, f = r / 8, hh = r % 8;
    float s = 0.f;
    for (int k = 0; k < HD; ++k) s += ew[f * HD + k] * we[l * 1600 + k * 8 + hh];
    Mm[tid] = s;   // l*48 + f*8 + hh
  } else if (tid < NL * 6 * 8 + NL * 8) {
    int u = tid - NL * 6 * 8, l = u / 8, hh = u % 8;
    float s = 0.f;
    for (int k = 0; k < HD; ++k) s += eb[k] * we[l * 1600 + k * 8 + hh];
    cv[u] = s;
  }
}

// a_e for real edges, all layers: ae[l][e][h] = edge_attr[e] . M[l][:,h] + cvec[l][h]
__global__ __launch_bounds__(256) void k_ae_edge(const float* __restrict__ ea, const float* __restrict__ Mm,
                                                 const float* __restrict__ cv, float* __restrict__ ae, int E) {
  int e = blockIdx.x * 256 + threadIdx.x;
  if (e >= E) return;
  float v[6];
#pragma unroll
  for (int f = 0; f < 6; ++f) v[f] = ea[(size_t)e * 6 + f];
  for (int l = 0; l < NL; ++l)
#pragma unroll
    for (int hh = 0; hh < 8; ++hh) {
      float s = cv[l * 8 + hh];
#pragma unroll
      for (int f = 0; f < 6; ++f) s += v[f] * Mm[l * 48 + f * 8 + hh];
      ae[(size_t)l * E * 8 + (size_t)e * 8 + hh] = s;
    }
}

// a_e for self loops: loop_attr = deg>0 ? mean_ea@We + be : 0  ->  ae_s = loop_attr @ w_e
__global__ __launch_bounds__(256) void k_ae_self(const float* __restrict__ mea, const int* __restrict__ cnt,
                                                 const float* __restrict__ Mm, const float* __restrict__ cv,
                                                 float* __restrict__ aes, int N) {
  int n = blockIdx.x * 256 + threadIdx.x;
  if (n >= N) return;
  bool has = cnt[n] > 0;
  float v[6];
#pragma unroll
  for (int f = 0; f < 6; ++f) v[f] = mea[(size_t)n * 6 + f];
  for (int l = 0; l < NL; ++l)
#pragma unroll
    for (int hh = 0; hh < 8; ++hh) {
      float s = 0.f;
      if (has) {
        s = cv[l * 8 + hh];
#pragma unroll
        for (int f = 0; f < 6; ++f) s += v[f] * Mm[l * 48 + f * 8 + hh];
      }
      aes[(size_t)l * N * 8 + (size_t)n * 8 + hh] = s;
    }
}

// ---------------- GEMM: C[M,200] = A[M,K] @ B[K,200] (+bias) (+accumulate) ----------------
// BM=64, BN=200 (full width), BK=8; 320 threads; per-thread 4 rows x 10 cols
__global__ __launch_bounds__(320) void k_gemm200(const float* __restrict__ A, const float* __restrict__ B,
                                                 const float* __restrict__ bias, float* __restrict__ C,
                                                 int M, int K, int accumulate) {
  __shared__ float As[64][9];     // +1 pad breaks 4-way bank conflict
  __shared__ float Bs[8][HD];
  int t = threadIdx.x;
  int cg = t % 20;                // cols cg*10 .. +9
  int rg = t / 20;                // rows rg*4 .. +3
  int row0 = blockIdx.x * 64;
  float acc[4][10] = {};
  for (int k0 = 0; k0 < K; k0 += 8) {
    for (int idx = t; idx < 64 * 8; idx += 320) {
      int r = idx >> 3, kk = idx & 7;
      int gr = row0 + r;
      As[r][kk] = (gr < M) ? A[(size_t)gr * K + k0 + kk] : 0.f;
    }
    for (int idx = t; idx < 8 * HD; idx += 320) {
      int kk = idx / HD, c = idx % HD;
      Bs[kk][c] = B[(size_t)(k0 + kk) * HD + c];
    }
    __syncthreads();
#pragma unroll
    for (int kk = 0; kk < 8; ++kk) {
      float a0 = As[rg * 4 + 0][kk], a1 = As[rg * 4 + 1][kk];
      float a2 = As[rg * 4 + 2][kk], a3 = As[rg * 4 + 3][kk];
#pragma unroll
      for (int j = 0; j < 10; ++j) {
        float b = Bs[kk][cg * 10 + j];
        acc[0][j] += a0 * b; acc[1][j] += a1 * b; acc[2][j] += a2 * b; acc[3][j] += a3 * b;
      }
    }
    __syncthreads();
  }
#pragma unroll
  for (int i = 0; i < 4; ++i) {
    int r = row0 + rg * 4 + i;
    if (r < M) {
#pragma unroll
      for (int j = 0; j < 10; ++j) {
        int c = cg * 10 + j;
        float v = acc[i][j];
        if (bias) v += bias[c];
        if (accumulate) v += C[(size_t)r * HD + c];
        C[(size_t)r * HD + c] = v;
      }
    }
  }
}

// a_src[n,h] = sum_c xs[n,h*25+c]*att_src[h,c]; same for a_dst
__global__ __launch_bounds__(256) void k_asrcdst(const float* __restrict__ xs, const float* __restrict__ as_l,
                                                 const float* __restrict__ ad_l, float* __restrict__ a_src,
                                                 float* __restrict__ a_dst, int N) {
  int tid = blockIdx.x * 256 + threadIdx.x;
  if (tid >= N * 8) return;
  int n = tid >> 3, hh = tid & 7;
  const float* xr = xs + (size_t)n * HD + hh * CD;
  const float* sa = as_l + hh * CD;
  const float* da = ad_l + hh * CD;
  float s = 0.f, d = 0.f;
#pragma unroll
  for (int c = 0; c < CD; ++c) { float v = xr[c]; s += v * sa[c]; d += v * da[c]; }
  a_src[tid] = s; a_dst[tid] = d;
}

// ---------------- per-dst-node softmax aggregation; one wave per node ----------------
__global__ __launch_bounds__(256) void k_aggr(const float* __restrict__ xs, const float* __restrict__ a_src,
                                              const float* __restrict__ a_dst, const float* __restrict__ ae_e,
                                              const float* __restrict__ ae_s, const float* __restrict__ gb,
                                              const int* __restrict__ off, const int* __restrict__ eid,
                                              const int* __restrict__ esrc, float* __restrict__ h_out, int N) {
  int lane = threadIdx.x & 63;
  int node = blockIdx.x * 4 + (threadIdx.x >> 6);
  if (node >= N) return;
  int o0 = off[node], o1 = off[node + 1];
  // column->head mapping for this lane's 4 owned columns (lane, +64, +128, +192)
  int hh0 = lane / 25, hh1 = (lane + 64) / 25, hh2 = (lane + 128) / 25, hh3 = (lane + 192) / 25;
  float adsth = 0.f, aself = 0.f, aes = 0.f, mx = -1e30f;
  if (lane < 8) {
    adsth = a_dst[(size_t)node * 8 + lane];
    aself = a_src[(size_t)node * 8 + lane];
    aes   = ae_s[(size_t)node * 8 + lane];
    float l0 = aself + adsth + aes;
    mx = (l0 >= 0.f) ? l0 : 0.2f * l0;
  }
  // pass 1: max logit per head (lanes 0..7)
  for (int p = o0; p < o1; ++p) {
    int e = eid[p], s = esrc[e];
    if (lane < 8) {
      float l0 = a_src[(size_t)s * 8 + lane] + adsth + ae_e[(size_t)e * 8 + lane];
      l0 = (l0 >= 0.f) ? l0 : 0.2f * l0;
      mx = fmaxf(mx, l0);
    }
  }
  // pass 2: exp-weights (lanes 0..7), broadcast via shuffle, accumulate columns
  float acc0 = 0.f, acc1 = 0.f, acc2 = 0.f, acc3 = 0.f, ssum = 0.f;
  {
    float w = 0.f;
    if (lane < 8) {
      float l0 = aself + adsth + aes;
      l0 = (l0 >= 0.f) ? l0 : 0.2f * l0;
      w = expf(l0 - mx); ssum += w;
    }
    float wa = __shfl(w, hh0), wb = __shfl(w, hh1), wc = __shfl(w, hh2), wd = __shfl(w, hh3);
    const float* xr = xs + (size_t)node * HD;
    acc0 += wa * xr[lane]; acc1 += wb * xr[lane + 64]; acc2 += wc * xr[lane + 128];
    if (lane < 8) acc3 += wd * xr[lane + 192];
  }
  for (int p = o0; p < o1; ++p) {
    int e = eid[p], s = esrc[e];
    float w = 0.f;
    if (lane < 8) {
      float l0 = a_src[(size_t)s * 8 + lane] + adsth + ae_e[(size_t)e * 8 + lane];
      l0 = (l0 >= 0.f) ? l0 : 0.2f * l0;
      w = expf(l0 - mx); ssum += w;
    }
    float wa = __shfl(w, hh0), wb = __shfl(w, hh1), wc = __shfl(w, hh2), wd = __shfl(w, hh3);
    const float* xr = xs + (size_t)s * HD;
    acc0 += wa * xr[lane]; acc1 += wb * xr[lane + 64]; acc2 += wc * xr[lane + 128];
    if (lane < 8) acc3 += wd * xr[lane + 192];
  }
  float sa = __shfl(ssum, hh0) + 1e-16f, sb = __shfl(ssum, hh1) + 1e-16f;
  float sc = __shfl(ssum, hh2) + 1e-16f, sd = __shfl(ssum, hh3) + 1e-16f;
  float* ho = h_out + (size_t)node * HD;
  ho[lane]       = acc0 / sa + gb[lane];
  ho[lane + 64]  = acc1 / sb + gb[lane + 64];
  ho[lane + 128] = acc2 / sc + gb[lane + 128];
  if (lane < 8) ho[lane + 192] = acc3 / sd + gb[lane + 192];
}

// graph start offsets from sorted batch
__global__ __launch_bounds__(256) void k_gstart(const int* __restrict__ batch, int* __restrict__ gstart,
                                                int N, int G) {
  int i = blockIdx.x * 256 + threadIdx.x;
  if (i >= N) return;
  int b = batch[i];
  int pb = (i == 0) ? -1 : batch[i - 1];
  for (int g = pb + 1; g <= b; ++g) gstart[g] = i;
  if (i == N - 1) for (int g = b + 1; g <= G; ++g) gstart[g] = N;
}

__global__ __launch_bounds__(256) void k_pool(const float* __restrict__ h, const int* __restrict__ gstart,
                                              float* __restrict__ pooled, int G) {
  int g = blockIdx.x, c = threadIdx.x;
  if (c >= HD) return;
  int s0 = gstart[g], s1 = gstart[g + 1];
  float acc = 0.f;
  for (int i = s0; i < s1; ++i) acc += h[(size_t)i * HD + c];
  pooled[(size_t)g * HD + c] = acc;
}

// task heads: one wave per (t,g)
__global__ __launch_bounds__(256) void k_heads(const float* __restrict__ ro, const float* __restrict__ w1,
                                               const float* __restrict__ b1, const float* __restrict__ w2,
                                               const float* __restrict__ b2, float* __restrict__ out, int G) {
  int lane = threadIdx.x & 63;
  int idx = blockIdx.x * 4 + (threadIdx.x >> 6);
  if (idx >= 5 * G) return;
  int t = idx / G, g = idx % G;
  const float* r = ro + (size_t)g * HD;
  const float* W = w1 + (size_t)t * HD * 100;
  bool has2 = lane < 36;
  float h0 = 0.f, h1 = 0.f;
  for (int k = 0; k < HD; ++k) {
    float rv = r[k];
    h0 += rv * W[k * 100 + lane];
    if (has2) h1 += rv * W[k * 100 + 64 + lane];
  }
  h0 += b1[t * 100 + lane];
  h0 = h0 > 0.f ? h0 : 0.f;
  float p = h0 * w2[t * 100 + lane];
  if (has2) {
    h1 += b1[t * 100 + 64 + lane];
    h1 = h1 > 0.f ? h1 : 0.f;
    p += h1 * w2[t * 100 + 64 + lane];
  }
  for (int o = 32; o >= 1; o >>= 1) p += __shfl_down(p, o);
  if (lane == 0) {
    float z = p + b2[t];
    bool sig = (t == 0) | (t == 3) | (t == 4);   // SIG = {1,0,0,1,1}
    out[idx] = sig ? 1.f / (1.f + expf(-z)) : z;
  }
}

extern "C" void kernel_launch(void* const* d_in, const int* in_sizes, int n_in,
                              void* d_out, int out_size, void* d_ws, size_t ws_size,
                              hipStream_t stream) {
  const float* x         = (const float*)d_in[0];
  const float* edge_attr = (const float*)d_in[1];
  const float* node_w    = (const float*)d_in[2];
  const float* node_b    = (const float*)d_in[3];
  const float* edge_w    = (const float*)d_in[4];
  const float* edge_b    = (const float*)d_in[5];
  const float* lin_w     = (const float*)d_in[6];
  const float* lin_edge_w= (const float*)d_in[7];
  const float* att_src   = (const float*)d_in[8];
  const float* att_dst   = (const float*)d_in[9];
  const float* att_edge  = (const float*)d_in[10];
  const float* gat_bias  = (const float*)d_in[11];
  const float* readout_w = (const float*)d_in[12];
  const float* readout_b = (const float*)d_in[13];
  const float* head_w1   = (const float*)d_in[14];
  const float* head_b1   = (const float*)d_in[15];
  const float* head_w2   = (const float*)d_in[16];
  const float* head_b2   = (const float*)d_in[17];
  const int*   edge_index= (const int*)d_in[18];
  const int*   batch     = (const int*)d_in[19];

  const int N = in_sizes[0] / 64;
  const int E = in_sizes[1] / 6;
  const int G = out_size / 5;
  const int* srcI = edge_index;
  const int* dstI = edge_index + E;

  char* wsb = (char*)d_ws;
  size_t o = 0;
  auto alloc = [&](size_t bytes) -> void* {
    void* p = wsb + o;
    o = (o + bytes + 255) & ~(size_t)255;
    return p;
  };
  float* h       = (float*)alloc((size_t)N * HD * 4);
  float* xs      = (float*)alloc((size_t)N * HD * 4);
  float* a_src   = (float*)alloc((size_t)N * 8 * 4);
  float* a_dst   = (float*)alloc((size_t)N * 8 * 4);
  float* ae_e    = (float*)alloc((size_t)NL * E * 8 * 4);
  float* ae_s    = (float*)alloc((size_t)NL * N * 8 * 4);
  float* mean_ea = (float*)alloc((size_t)N * 6 * 4);
  float* we      = (float*)alloc((size_t)NL * HD * 8 * 4);
  float* Mm      = (float*)alloc((size_t)NL * 6 * 8 * 4);
  float* cv      = (float*)alloc((size_t)NL * 8 * 4);
  int* cnt       = (int*)alloc((size_t)N * 4);
  int* cur       = (int*)alloc((size_t)N * 4);
  int* off       = (int*)alloc((size_t)(N + 1) * 4);
  int* partial   = (int*)alloc(512 * 4);
  int* eid       = (int*)alloc((size_t)E * 4);
  int* gstart    = (int*)alloc((size_t)(G + 1) * 4);
  float* pooled  = (float*)alloc((size_t)G * HD * 4);
  float* readouts= (float*)alloc((size_t)G * HD * 4);
  (void)ws_size; (void)n_in;

  hipMemsetAsync(cnt, 0, (size_t)N * 4, stream);
  hipMemsetAsync(cur, 0, (size_t)N * 4, stream);
  hipMemsetAsync(readouts, 0, (size_t)G * HD * 4, stream);

  int nb = (N + 255) / 256;
  k_hist<<<(E + 255) / 256, 256, 0, stream>>>(dstI, cnt, E);
  k_scan1<<<nb, 256, 0, stream>>>(cnt, off, partial, N);
  k_scan2<<<1, 512, 0, stream>>>(partial, nb, off, N);
  k_scan3<<<nb, 256, 0, stream>>>(off, partial, N);
  k_scatter<<<(E + 255) / 256, 256, 0, stream>>>(dstI, off, cur, eid, E);
  k_sort<<<nb, 256, 0, stream>>>(off, eid, N);
  k_meanea<<<(N + 127) / 128, 128, 0, stream>>>(edge_attr, off, eid, mean_ea, N);
  k_we<<<(NL * HD * 8 + 255) / 256, 256, 0, stream>>>(lin_edge_w, att_edge, we);
  k_M<<<1, 256, 0, stream>>>(edge_w, edge_b, we, Mm, cv);
  k_ae_edge<<<(E + 255) / 256, 256, 0, stream>>>(edge_attr, Mm, cv, ae_e, E);
  k_ae_self<<<(N + 255) / 256, 256, 0, stream>>>(mean_ea, cnt, Mm, cv, ae_s, N);
  k_gemm200<<<(N + 63) / 64, 320, 0, stream>>>(x, node_w, node_b, h, N, 64, 0);
  k_gstart<<<nb, 256, 0, stream>>>(batch, gstart, N, G);

  for (int l = 0; l < NL; ++l) {
    k_gemm200<<<(N + 63) / 64, 320, 0, stream>>>(h, lin_w + (size_t)l * HD * HD, nullptr, xs, N, HD, 0);
    k_asrcdst<<<(N * 8 + 255) / 256, 256, 0, stream>>>(xs, att_src + l * NH * CD, att_dst + l * NH * CD,
                                                       a_src, a_dst, N);
    k_aggr<<<(N + 3) / 4, 256, 0, stream>>>(xs, a_src, a_dst, ae_e + (size_t)l * E * 8,
                                            ae_s + (size_t)l * N * 8, gat_bias + l * HD,
                                            off, eid, srcI, h, N);
    k_pool<<<G, 256, 0, stream>>>(h, gstart, pooled, G);
    k_gemm200<<<(G + 63) / 64, 320, 0, stream>>>(pooled, readout_w + (size_t)l * HD * HD,
                                                 readout_b + l * HD, readouts, G, HD, 1);
  }
  k_heads<<<(5 * G + 3) / 4, 256, 0, stream>>>(readouts, head_w1, head_b1, head_w2, head_b2,
                                               (float*)d_out, G);
}